// Round 3
// baseline (133.427 us; speedup 1.0000x reference)
//
#include <hip/hip_runtime.h>

// ExpertCompoundTracker: MoE load-EMA + pairwise co-activation histogram.
// Inputs: expert_indices [N,K] int32, expert_weights (UNUSED),
//         expert_load_ema [E] f32, expert_pair_coactivation [E,E] f32.
// Outputs concat: new_load_ema [64] then new_coact [4096], f32.
//
// R3: (a) XOR bank swizzle — raw cell lo*64+hi has bank hi%32 (skewed 2.9x
// since hi=max(pair)); storing at lo*64+(hi^(lo&31)) uniformizes banks.
// (b) 256x512 launch (same 8 waves/CU) halves flush global atomics.
// (c) fused finalize via last-block-done: kills one dispatch + cold reads.

#define N_TOKENS    2097152
#define NUM_EXPERTS 64
#define NCELLS      (NUM_EXPERTS * NUM_EXPERTS)  // 4096
#define NBLOCKS     256
#define NTHREADS    512

__device__ __forceinline__ void pair_add(int* s, int a, int b) {
    const int lo = min(a, b), hi = max(a, b);
    // swizzled cell: bijective, bank = (hi%32) ^ (lo&31) -> uniform
    atomicAdd(&s[(lo << 6) + (hi ^ (lo & 31))], 1);
}

__global__ __launch_bounds__(NTHREADS) void coact_fused_kernel(
    const int* __restrict__ idx,
    const float* __restrict__ ema_in,
    const float* __restrict__ coact_in,
    int* __restrict__ ws,            // [NCELLS] histogram + [NCELLS] done-flag
    float* __restrict__ out)
{
    __shared__ int s_coact[NCELLS];  // 16 KB, swizzled upper-triangle cells
    __shared__ int s_last;
    for (int i = threadIdx.x; i < NCELLS; i += NTHREADS) s_coact[i] = 0;
    __syncthreads();

    const int tid    = blockIdx.x * NTHREADS + threadIdx.x;
    const int stride = NBLOCKS * NTHREADS;           // 131072 -> 16 tokens/thread
    const int4* __restrict__ idx4 = (const int4*)idx;

    #pragma unroll 4
    for (int t = tid; t < N_TOKENS; t += stride) {
        int4 v = idx4[t];
        pair_add(s_coact, v.x, v.y);
        pair_add(s_coact, v.x, v.z);
        pair_add(s_coact, v.x, v.w);
        pair_add(s_coact, v.y, v.z);
        pair_add(s_coact, v.y, v.w);
        pair_add(s_coact, v.z, v.w);
    }
    __syncthreads();

    // Flush: unswizzle, skip zeros (lower triangle stays zero in ws too).
    for (int i = threadIdx.x; i < NCELLS; i += NTHREADS) {
        int v = s_coact[i];
        if (v) {
            const int lo = i >> 6;
            const int hi = (i & 63) ^ (lo & 31);
            atomicAdd(&ws[(lo << 6) + hi], v);
        }
    }

    // Last-block-done: release fence + device-scope counter.
    __threadfence();
    if (threadIdx.x == 0) {
        const int done = atomicAdd(&ws[NCELLS], 1);
        s_last = (done == NBLOCKS - 1) ? 1 : 0;
    }
    __syncthreads();
    if (!s_last) return;

    __threadfence();  // acquire side, all threads of last block

    // new_coact: mirror upper-triangle ws (diagonal x2 — reference adds
    // .at[a,b] and .at[b,a]).
    for (int c = threadIdx.x; c < NCELLS; c += NTHREADS) {
        const int i = c >> 6, j = c & 63;
        const int lo = min(i, j), hi = max(i, j);
        int d = ws[(lo << 6) + hi];
        if (i == j) d *= 2;
        out[NUM_EXPERTS + c] = coact_in[c] + (float)d;
    }

    // counts[e] = rowsum(sym delta)/3 exactly (each occurrence of e pairs
    // with the other 3 slots, duplicates included). L1-warm after loop above.
    if (threadIdx.x < NUM_EXPERTS) {
        const int t = threadIdx.x;
        int rowsum = 0;
        #pragma unroll
        for (int j = 0; j < NUM_EXPERTS; ++j) {
            const int lo = min(t, j), hi = max(t, j);
            int d = ws[(lo << 6) + hi];
            rowsum += (j == t) ? 2 * d : d;
        }
        const int count = rowsum / 3;
        const float load = (float)count / (float)N_TOKENS;
        out[t] = ema_in[t] * 0.99f + load * 0.01f;
    }
}

extern "C" void kernel_launch(void* const* d_in, const int* in_sizes, int n_in,
                              void* d_out, int out_size, void* d_ws, size_t ws_size,
                              hipStream_t stream)
{
    const int*   idx      = (const int*)d_in[0];
    // d_in[1] = expert_weights: unused by the reference -> never read.
    const float* ema_in   = (const float*)d_in[2];
    const float* coact_in = (const float*)d_in[3];
    float*       out      = (float*)d_out;
    int*         ws       = (int*)d_ws;

    // Zero histogram + done-counter (ws is re-poisoned 0xAA each iteration).
    hipMemsetAsync(ws, 0, (NCELLS + 1) * sizeof(int), stream);

    coact_fused_kernel<<<NBLOCKS, NTHREADS, 0, stream>>>(idx, ema_in, coact_in, ws, out);
}